// Round 24
// baseline (69.177 us; speedup 1.0000x reference)
//
#include <hip/hip_runtime.h>
#include <math.h>

// Capsule dynamic routing v25 — v24 + prefetch-2 x (5 barriers) + setprio routing.
// R23: v24 neutral — aliased staging's 7us VMEM saving eaten by 9 in-loop
// barriers. v25:
//  (1) even j reads x slices j AND j+1 into regs; ONE barrier then covers
//      park[j] and park[j+1] (slice j+1's readers all precede the barrier —
//      __syncthreads drains lgkmcnt). 9 -> 5 barriers, +16 VGPR.
//  (2) s_setprio(1) around routing sweeps: resident blocks drift anti-phase
//      (one priors/VMEM, one routing/VALU+DS) — the independent-block case
//      where setprio measured +4-7%; favors the tail-critical routing waves.
// Everything else v24 verbatim (proven: 52.1us, VGPR 64, 0 conflicts).
//
// x: [B=256, R=1152, I=8] f32 ; W: [C=10, R=1152, I=8, O=16] f32
// out: [B=256, C=10, O=16] f32
//
// Shared buffer (73728B), slice j = bytes [j*8192,(j+1)*8192):
//   before iter j: x slice j = [bsel][128 rows][8] f32
//   after  iter j: park[j]   = [bsel][512 thr] uint2 (fp16x4)
//
// One block per (c, b-pair). T=512, 8 waves, ~76KB LDS -> 2 blocks/CU.
// Priors: g=t>>2, q=t&3; rows r=g+j*128, j=0..8; both batches (G=2 fan-out).
// Routing: q2=t&3, bsel=t>>8, p_lo=t&255; rows r=g2+jj*64, jj=0..17.

#define C_CAPS 10
#define B_SZ   256
#define R_SZ   1152
#define I_SZ   8
#define O_SZ   16
#define T_THREADS 512
#define RPT_P 9
#define RPT_R 18
#define NW 8

static __device__ __forceinline__ unsigned int pack2h(float a, float b) {
    const _Float16 ha = (_Float16)a, hb = (_Float16)b;
    const unsigned short ua = __builtin_bit_cast(unsigned short, ha);
    const unsigned short ub = __builtin_bit_cast(unsigned short, hb);
    return (unsigned int)ua | ((unsigned int)ub << 16);
}
static __device__ __forceinline__ float h2f_lo(unsigned int u) {
    const _Float16 h = __builtin_bit_cast(_Float16, (unsigned short)(u & 0xffffu));
    return (float)h;
}
static __device__ __forceinline__ float h2f_hi(unsigned int u) {
    const _Float16 h = __builtin_bit_cast(_Float16, (unsigned short)(u >> 16));
    return (float)h;
}

__global__ __launch_bounds__(T_THREADS, 1) void capsule_kernel(
    const float* __restrict__ x,
    const float* __restrict__ w,
    float* __restrict__ out)
{
    const int c  = blockIdx.x >> 7;        // / (B/2)
    const int bb = blockIdx.x & 127;
    const int b0 = bb * 2;
    const int t = (int)threadIdx.x;
    const int lane = t & 63;
    const int wid = t >> 6;

    __shared__ float4 shbuf4[4608];                // 73728 B shared x/park
    float* shf = (float*)shbuf4;
    char*  shc = (char*)shbuf4;
    __shared__ float4 red_p0[NW][2][4];            // pass0 partials
    __shared__ float4 red_s[2][NW][4];             // parity, wave, q2
    __shared__ float  red_z[2][NW];

    // ========== phase A: cooperative x staging (9 linear dwordx4/thread) ====
    {
        const float* xsrc = x + (size_t)b0 * R_SZ * I_SZ;   // 18432 floats
        #pragma unroll
        for (int s = 0; s < 9; ++s) {
            const int f = s * (T_THREADS * 4) + t * 4;
            const int bsl = f / 9216;
            const int rem = f - bsl * 9216;
            const int row = rem >> 3;
            const int i   = rem & 7;
            const int dst = ((row >> 7) << 11) + (bsl << 10) + ((row & 127) << 3) + i;
            *(float4*)&shf[dst] = *(const float4*)(xsrc + f);
        }
    }
    __syncthreads();

    // ========== phase B: priors G=2 fan-out; prefetch-2 x; 5 barriers ========
    {
        const int g = t >> 2;              // 0..127
        const int q = t & 3;
        const float* wr = w + ((size_t)c * R_SZ + g) * (I_SZ * O_SZ) + q * 4;
        const size_t wstep = (size_t)128 * I_SZ * O_SZ;

        float s00 = 0.f, s01 = 0.f, s02 = 0.f, s03 = 0.f;   // pass0 sums b0
        float s10 = 0.f, s11 = 0.f, s12 = 0.f, s13 = 0.f;   // pass0 sums b0+1

        float4 px0a, px0b, px1a, px1b;     // prefetched x for odd iters

        #pragma unroll
        for (int j = 0; j < RPT_P; ++j) {
            float xi0[I_SZ], xi1[I_SZ];
            if ((j & 1) == 0) {
                // read slice j (and prefetch slice j+1) from LDS
                const int xb = (j << 11) + (g << 3);
                const float4 a0 = *(const float4*)&shf[xb];
                const float4 b0v = *(const float4*)&shf[xb + 4];
                const float4 a1 = *(const float4*)&shf[xb + 1024];
                const float4 b1v = *(const float4*)&shf[xb + 1028];
                xi0[0]=a0.x; xi0[1]=a0.y; xi0[2]=a0.z; xi0[3]=a0.w;
                xi0[4]=b0v.x; xi0[5]=b0v.y; xi0[6]=b0v.z; xi0[7]=b0v.w;
                xi1[0]=a1.x; xi1[1]=a1.y; xi1[2]=a1.z; xi1[3]=a1.w;
                xi1[4]=b1v.x; xi1[5]=b1v.y; xi1[6]=b1v.z; xi1[7]=b1v.w;
                if (j + 1 < RPT_P) {
                    px0a = *(const float4*)&shf[xb + 2048];
                    px0b = *(const float4*)&shf[xb + 2052];
                    px1a = *(const float4*)&shf[xb + 3072];
                    px1b = *(const float4*)&shf[xb + 3076];
                }
            } else {
                xi0[0]=px0a.x; xi0[1]=px0a.y; xi0[2]=px0a.z; xi0[3]=px0a.w;
                xi0[4]=px0b.x; xi0[5]=px0b.y; xi0[6]=px0b.z; xi0[7]=px0b.w;
                xi1[0]=px1a.x; xi1[1]=px1a.y; xi1[2]=px1a.z; xi1[3]=px1a.w;
                xi1[4]=px1b.x; xi1[5]=px1b.y; xi1[6]=px1b.z; xi1[7]=px1b.w;
            }

            const float* wj = wr + j * wstep;
            float a00=0.f, a01=0.f, a02=0.f, a03=0.f;
            float a10=0.f, a11=0.f, a12=0.f, a13=0.f;
            #pragma unroll
            for (int i = 0; i < I_SZ; ++i) {
                const float4 wv = *(const float4*)(wj + i * O_SZ);  // feeds 8 FMA
                a00 = fmaf(xi0[i], wv.x, a00);
                a01 = fmaf(xi0[i], wv.y, a01);
                a02 = fmaf(xi0[i], wv.z, a02);
                a03 = fmaf(xi0[i], wv.w, a03);
                a10 = fmaf(xi1[i], wv.x, a10);
                a11 = fmaf(xi1[i], wv.y, a11);
                a12 = fmaf(xi1[i], wv.z, a12);
                a13 = fmaf(xi1[i], wv.w, a13);
            }
            if ((j & 1) == 0) __syncthreads();
            // barrier(j even) covers park[j] AND park[j+1]: every thread's
            // slice-j and slice-j+1 reads (incl. prefetch) precede it
            // (__syncthreads drains lgkmcnt), all park writes follow it.
            uint2 p0, p1;
            p0.x = pack2h(a00, a01); p0.y = pack2h(a02, a03);
            p1.x = pack2h(a10, a11); p1.y = pack2h(a12, a13);
            *(uint2*)(shc + (j << 13) + (t << 3))        = p0;
            *(uint2*)(shc + (j << 13) + 4096 + (t << 3)) = p1;
            s00 += a00; s01 += a01; s02 += a02; s03 += a03;
            s10 += a10; s11 += a11; s12 += a12; s13 += a13;
        }

        // pass0 reduce in priors layout: 16 groups per wave (masks 4..32)
        #pragma unroll
        for (int m = 4; m <= 32; m <<= 1) {
            s00 += __shfl_xor(s00, m, 64); s01 += __shfl_xor(s01, m, 64);
            s02 += __shfl_xor(s02, m, 64); s03 += __shfl_xor(s03, m, 64);
            s10 += __shfl_xor(s10, m, 64); s11 += __shfl_xor(s11, m, 64);
            s12 += __shfl_xor(s12, m, 64); s13 += __shfl_xor(s13, m, 64);
        }
        if (lane < 4) {
            red_p0[wid][0][lane] = make_float4(s00, s01, s02, s03);
            red_p0[wid][1][lane] = make_float4(s10, s11, s12, s13);
        }
    }
    __syncthreads();     // park complete + pass0 partials visible

    // ================= phase C: routing (2 fused sweeps, prio-boosted) =======
    const int q2   = t & 3;
    const int bsel = t >> 8;
    const int p_lo = t & 255;

    float logit[RPT_R];
    #pragma unroll
    for (int jj = 0; jj < RPT_R; ++jj) logit[jj] = 0.0f;

    float vq[4];

    // -------- pass 0: combine pre-reduced sums; Z = 1152 exactly --------
    {
        float4 sf = red_p0[0][bsel][q2];
        #pragma unroll
        for (int ww = 1; ww < NW; ++ww) {
            const float4 rr = red_p0[ww][bsel][q2];
            sf.x += rr.x; sf.y += rr.y; sf.z += rr.z; sf.w += rr.w;
        }
        const float invZ = 1.0f / (float)R_SZ;
        const float u0 = sf.x * invZ, u1 = sf.y * invZ,
                    u2 = sf.z * invZ, u3 = sf.w * invZ;
        float nq = u0*u0 + u1*u1 + u2*u2 + u3*u3;
        nq += __shfl_xor(nq, 1, 64);
        nq += __shfl_xor(nq, 2, 64);
        const float scale = nq / ((1.0f + nq) * sqrtf(nq));
        vq[0] = scale * u0; vq[1] = scale * u1;
        vq[2] = scale * u2; vq[3] = scale * u3;
    }

    __builtin_amdgcn_s_setprio(1);     // favor routing waves vs priors VMEM
    // -------- passes 1,2: fused logit-update + exp + s-accum --------
    #pragma unroll
    for (int p = 1; p < 3; ++p) {
        const int pb = p & 1;
        float sa0 = 0.f, sa1 = 0.f, sa2 = 0.f, sa3 = 0.f, zp = 0.f;
        #pragma unroll
        for (int jj = 0; jj < RPT_R; ++jj) {
            const uint2 pp = *(const uint2*)(shc + ((jj >> 1) << 13)
                              + (bsel << 12) + ((p_lo | ((jj & 1) << 8)) << 3));
            const float P0 = h2f_lo(pp.x), P1 = h2f_hi(pp.x);
            const float P2 = h2f_lo(pp.y), P3 = h2f_hi(pp.y);
            float d = P0*vq[0] + P1*vq[1] + P2*vq[2] + P3*vq[3];
            d += __shfl_xor(d, 1, 64);
            d += __shfl_xor(d, 2, 64);
            logit[jj] += d;
            const float e = __expf(logit[jj]);     // |logit|<=~40: f32-safe
            zp += e;
            sa0 = fmaf(e, P0, sa0);
            sa1 = fmaf(e, P1, sa1);
            sa2 = fmaf(e, P2, sa2);
            sa3 = fmaf(e, P3, sa3);
        }
        #pragma unroll
        for (int m = 4; m <= 32; m <<= 1) {
            sa0 += __shfl_xor(sa0, m, 64);
            sa1 += __shfl_xor(sa1, m, 64);
            sa2 += __shfl_xor(sa2, m, 64);
            sa3 += __shfl_xor(sa3, m, 64);
            zp  += __shfl_xor(zp,  m, 64);
        }
        if (lane < 4) red_s[pb][wid][lane] = make_float4(sa0, sa1, sa2, sa3);
        if (lane == 0) red_z[pb][wid] = zp;
        __syncthreads();

        const int wbase = bsel << 2;
        float4 sf = red_s[pb][wbase][q2];
        float Z = red_z[pb][wbase];
        #pragma unroll
        for (int k = 1; k < 4; ++k) {
            const float4 rr = red_s[pb][wbase + k][q2];
            sf.x += rr.x; sf.y += rr.y; sf.z += rr.z; sf.w += rr.w;
            Z += red_z[pb][wbase + k];
        }
        const float invZ = 1.0f / Z;
        const float u0 = sf.x * invZ, u1 = sf.y * invZ,
                    u2 = sf.z * invZ, u3 = sf.w * invZ;
        float nq = u0*u0 + u1*u1 + u2*u2 + u3*u3;
        nq += __shfl_xor(nq, 1, 64);
        nq += __shfl_xor(nq, 2, 64);
        const float scale = nq / ((1.0f + nq) * sqrtf(nq));
        vq[0] = scale * u0; vq[1] = scale * u1;
        vq[2] = scale * u2; vq[3] = scale * u3;
    }
    __builtin_amdgcn_s_setprio(0);

    // ---- write out[b0+bsel, c, :] — one thread per (bsel, q2) ----
    if ((t & 255) < 4) {
        float* op = out + ((size_t)(b0 + bsel) * C_CAPS + c) * O_SZ + q2 * 4;
        *(float4*)op = make_float4(vq[0], vq[1], vq[2], vq[3]);
    }
}

extern "C" void kernel_launch(void* const* d_in, const int* in_sizes, int n_in,
                              void* d_out, int out_size, void* d_ws, size_t ws_size,
                              hipStream_t stream) {
    const float* x = (const float*)d_in[0];
    const float* w = (const float*)d_in[1];
    float* out = (float*)d_out;
    dim3 grid(C_CAPS * (B_SZ / 2));
    dim3 block(T_THREADS);
    hipLaunchKernelGGL(capsule_kernel, grid, block, 0, stream, x, w, out);
}

// Round 25
// 52.053 us; speedup vs baseline: 1.3290x; 1.3290x over previous
//
#include <hip/hip_runtime.h>
#include <math.h>

// Capsule dynamic routing v26 — REVERT to v24 (proven 52.1us champion).
// R24: v25's bundle (prefetch-2 + setprio) regressed to 69us — setprio
// starved the critical-path priors waves of the co-resident block
// (occupancy 32->21%). Reverting verbatim to R23's kernel.
//
// v24 recap: aliased x-staging (x slice j consumed at priors-iter j is
// overwritten in place by park[j], one barrier per iter), G=2 W fan-out
// (one W float4 feeds 8 FMAs), pass0 sum folded into priors, v22's two
// fused routing sweeps with parity-buffered single-barrier reductions.
// LDS ~76KB -> 2 blocks/CU; VMEM 81 insts/thread (9 linear x + 72 W).
//
// x: [B=256, R=1152, I=8] f32 ; W: [C=10, R=1152, I=8, O=16] f32
// out: [B=256, C=10, O=16] f32
//
// Shared buffer layout (73728B), slice j = bytes [j*8192,(j+1)*8192):
//   before iter j: x slice j  = [bsel][128 rows][8] f32
//   after  iter j: park[j]    = [bsel][512 thr] uint2 (fp16x4)
//
// One block per (c, b-pair). T=512, 8 waves.
// Priors: g=t>>2 (128 groups), q=t&3; rows r=g+j*128, j=0..8; both batches.
// Routing: q2=t&3, bsel=t>>8, p_lo=t&255; rows r=g2+jj*64, jj=0..17.

#define C_CAPS 10
#define B_SZ   256
#define R_SZ   1152
#define I_SZ   8
#define O_SZ   16
#define T_THREADS 512
#define RPT_P 9
#define RPT_R 18
#define NW 8

static __device__ __forceinline__ unsigned int pack2h(float a, float b) {
    const _Float16 ha = (_Float16)a, hb = (_Float16)b;
    const unsigned short ua = __builtin_bit_cast(unsigned short, ha);
    const unsigned short ub = __builtin_bit_cast(unsigned short, hb);
    return (unsigned int)ua | ((unsigned int)ub << 16);
}
static __device__ __forceinline__ float h2f_lo(unsigned int u) {
    const _Float16 h = __builtin_bit_cast(_Float16, (unsigned short)(u & 0xffffu));
    return (float)h;
}
static __device__ __forceinline__ float h2f_hi(unsigned int u) {
    const _Float16 h = __builtin_bit_cast(_Float16, (unsigned short)(u >> 16));
    return (float)h;
}

__global__ __launch_bounds__(T_THREADS, 1) void capsule_kernel(
    const float* __restrict__ x,
    const float* __restrict__ w,
    float* __restrict__ out)
{
    const int c  = blockIdx.x >> 7;        // / (B/2)
    const int bb = blockIdx.x & 127;
    const int b0 = bb * 2;
    const int t = (int)threadIdx.x;
    const int lane = t & 63;
    const int wid = t >> 6;

    __shared__ float4 shbuf4[4608];                // 73728 B shared x/park
    float* shf = (float*)shbuf4;
    char*  shc = (char*)shbuf4;
    __shared__ float4 red_p0[NW][2][4];            // pass0 partials
    __shared__ float4 red_s[2][NW][4];             // parity, wave, q2
    __shared__ float  red_z[2][NW];

    // ========== phase A: cooperative x staging (9 linear dwordx4/thread) ====
    // global f32 index f = bsel*9216 + row*8 + i  ->
    // LDS float index   (row>>7)*2048 + bsel*1024 + (row&127)*8 + i
    {
        const float* xsrc = x + (size_t)b0 * R_SZ * I_SZ;   // 18432 floats contig
        #pragma unroll
        for (int s = 0; s < 9; ++s) {
            const int f = s * (T_THREADS * 4) + t * 4;
            const int bsl = f / 9216;
            const int rem = f - bsl * 9216;
            const int row = rem >> 3;
            const int i   = rem & 7;                         // 0 or 4
            const int dst = ((row >> 7) << 11) + (bsl << 10) + ((row & 127) << 3) + i;
            *(float4*)&shf[dst] = *(const float4*)(xsrc + f);
        }
    }
    __syncthreads();

    // ========== phase B: priors G=2 fan-out, park aliases consumed x ========
    {
        const int g = t >> 2;              // 0..127
        const int q = t & 3;
        const float* wr = w + ((size_t)c * R_SZ + g) * (I_SZ * O_SZ) + q * 4;
        const size_t wstep = (size_t)128 * I_SZ * O_SZ;

        float s00 = 0.f, s01 = 0.f, s02 = 0.f, s03 = 0.f;   // pass0 sums b0
        float s10 = 0.f, s11 = 0.f, s12 = 0.f, s13 = 0.f;   // pass0 sums b0+1

        #pragma unroll
        for (int j = 0; j < RPT_P; ++j) {
            // x slice j: float base j*2048 + bsel*1024 + g*8
            const int xb = (j << 11) + (g << 3);
            const float4 x0a = *(const float4*)&shf[xb];
            const float4 x0b = *(const float4*)&shf[xb + 4];
            const float4 x1a = *(const float4*)&shf[xb + 1024];
            const float4 x1b = *(const float4*)&shf[xb + 1028];
            const float xi0[I_SZ] = {x0a.x, x0a.y, x0a.z, x0a.w,
                                     x0b.x, x0b.y, x0b.z, x0b.w};
            const float xi1[I_SZ] = {x1a.x, x1a.y, x1a.z, x1a.w,
                                     x1b.x, x1b.y, x1b.z, x1b.w};
            const float* wj = wr + j * wstep;
            float a00=0.f, a01=0.f, a02=0.f, a03=0.f;
            float a10=0.f, a11=0.f, a12=0.f, a13=0.f;
            #pragma unroll
            for (int i = 0; i < I_SZ; ++i) {
                const float4 wv = *(const float4*)(wj + i * O_SZ);  // feeds 8 FMA
                a00 = fmaf(xi0[i], wv.x, a00);
                a01 = fmaf(xi0[i], wv.y, a01);
                a02 = fmaf(xi0[i], wv.z, a02);
                a03 = fmaf(xi0[i], wv.w, a03);
                a10 = fmaf(xi1[i], wv.x, a10);
                a11 = fmaf(xi1[i], wv.y, a11);
                a12 = fmaf(xi1[i], wv.z, a12);
                a13 = fmaf(xi1[i], wv.w, a13);
            }
            __syncthreads();   // all slice-j x reads done -> park[j] may write
            uint2 p0, p1;
            p0.x = pack2h(a00, a01); p0.y = pack2h(a02, a03);
            p1.x = pack2h(a10, a11); p1.y = pack2h(a12, a13);
            // park[j]: byte j*8192 + bsel*4096 + t*8 (thread-linear: free)
            *(uint2*)(shc + (j << 13) + (t << 3))        = p0;
            *(uint2*)(shc + (j << 13) + 4096 + (t << 3)) = p1;
            s00 += a00; s01 += a01; s02 += a02; s03 += a03;
            s10 += a10; s11 += a11; s12 += a12; s13 += a13;
        }

        // pass0 reduce in priors layout: 16 groups per wave (masks 4..32)
        #pragma unroll
        for (int m = 4; m <= 32; m <<= 1) {
            s00 += __shfl_xor(s00, m, 64); s01 += __shfl_xor(s01, m, 64);
            s02 += __shfl_xor(s02, m, 64); s03 += __shfl_xor(s03, m, 64);
            s10 += __shfl_xor(s10, m, 64); s11 += __shfl_xor(s11, m, 64);
            s12 += __shfl_xor(s12, m, 64); s13 += __shfl_xor(s13, m, 64);
        }
        if (lane < 4) {                        // lane == q for these lanes
            red_p0[wid][0][lane] = make_float4(s00, s01, s02, s03);
            red_p0[wid][1][lane] = make_float4(s10, s11, s12, s13);
        }
    }
    __syncthreads();     // park complete + pass0 partials visible

    // ================= phase C: routing (2 fused sweeps, v22) ================
    const int q2   = t & 3;
    const int bsel = t >> 8;               // waves 0-3: bsel 0; waves 4-7: bsel 1
    const int p_lo = t & 255;              // park-thread low index

    float logit[RPT_R];
    #pragma unroll
    for (int jj = 0; jj < RPT_R; ++jj) logit[jj] = 0.0f;

    float vq[4];

    // -------- pass 0: combine pre-reduced sums; Z = 1152 exactly --------
    {
        float4 sf = red_p0[0][bsel][q2];
        #pragma unroll
        for (int ww = 1; ww < NW; ++ww) {
            const float4 rr = red_p0[ww][bsel][q2];
            sf.x += rr.x; sf.y += rr.y; sf.z += rr.z; sf.w += rr.w;
        }
        const float invZ = 1.0f / (float)R_SZ;
        const float u0 = sf.x * invZ, u1 = sf.y * invZ,
                    u2 = sf.z * invZ, u3 = sf.w * invZ;
        float nq = u0*u0 + u1*u1 + u2*u2 + u3*u3;
        nq += __shfl_xor(nq, 1, 64);
        nq += __shfl_xor(nq, 2, 64);
        const float scale = nq / ((1.0f + nq) * sqrtf(nq));
        vq[0] = scale * u0; vq[1] = scale * u1;
        vq[2] = scale * u2; vq[3] = scale * u3;
    }

    // -------- passes 1,2: fused logit-update + exp + s-accum --------
    #pragma unroll
    for (int p = 1; p < 3; ++p) {
        const int pb = p & 1;
        float sa0 = 0.f, sa1 = 0.f, sa2 = 0.f, sa3 = 0.f, zp = 0.f;
        #pragma unroll
        for (int jj = 0; jj < RPT_R; ++jj) {
            // park slice jj>>1, idx p_lo | ((jj&1)<<8)
            const uint2 pp = *(const uint2*)(shc + ((jj >> 1) << 13)
                              + (bsel << 12) + ((p_lo | ((jj & 1) << 8)) << 3));
            const float P0 = h2f_lo(pp.x), P1 = h2f_hi(pp.x);
            const float P2 = h2f_lo(pp.y), P3 = h2f_hi(pp.y);
            float d = P0*vq[0] + P1*vq[1] + P2*vq[2] + P3*vq[3];
            d += __shfl_xor(d, 1, 64);             // sum the 4 o-quads
            d += __shfl_xor(d, 2, 64);
            logit[jj] += d;
            const float e = __expf(logit[jj]);     // |logit|<=~40: f32-safe
            zp += e;
            sa0 = fmaf(e, P0, sa0);
            sa1 = fmaf(e, P1, sa1);
            sa2 = fmaf(e, P2, sa2);
            sa3 = fmaf(e, P3, sa3);
        }
        #pragma unroll
        for (int m = 4; m <= 32; m <<= 1) {
            sa0 += __shfl_xor(sa0, m, 64);
            sa1 += __shfl_xor(sa1, m, 64);
            sa2 += __shfl_xor(sa2, m, 64);
            sa3 += __shfl_xor(sa3, m, 64);
            zp  += __shfl_xor(zp,  m, 64);
        }
        if (lane < 4) red_s[pb][wid][lane] = make_float4(sa0, sa1, sa2, sa3);
        if (lane == 0) red_z[pb][wid] = zp;
        __syncthreads();

        const int wbase = bsel << 2;
        float4 sf = red_s[pb][wbase][q2];
        float Z = red_z[pb][wbase];
        #pragma unroll
        for (int k = 1; k < 4; ++k) {
            const float4 rr = red_s[pb][wbase + k][q2];
            sf.x += rr.x; sf.y += rr.y; sf.z += rr.z; sf.w += rr.w;
            Z += red_z[pb][wbase + k];
        }
        const float invZ = 1.0f / Z;
        const float u0 = sf.x * invZ, u1 = sf.y * invZ,
                    u2 = sf.z * invZ, u3 = sf.w * invZ;
        float nq = u0*u0 + u1*u1 + u2*u2 + u3*u3;
        nq += __shfl_xor(nq, 1, 64);
        nq += __shfl_xor(nq, 2, 64);
        const float scale = nq / ((1.0f + nq) * sqrtf(nq));
        vq[0] = scale * u0; vq[1] = scale * u1;
        vq[2] = scale * u2; vq[3] = scale * u3;
    }

    // ---- write out[b0+bsel, c, :] — one thread per (bsel, q2) ----
    if ((t & 255) < 4) {                       // t = 0..3 (bsel 0), 256..259 (bsel 1)
        float* op = out + ((size_t)(b0 + bsel) * C_CAPS + c) * O_SZ + q2 * 4;
        *(float4*)op = make_float4(vq[0], vq[1], vq[2], vq[3]);
    }
}

extern "C" void kernel_launch(void* const* d_in, const int* in_sizes, int n_in,
                              void* d_out, int out_size, void* d_ws, size_t ws_size,
                              hipStream_t stream) {
    const float* x = (const float*)d_in[0];
    const float* w = (const float*)d_in[1];
    float* out = (float*)d_out;
    dim3 grid(C_CAPS * (B_SZ / 2));
    dim3 block(T_THREADS);
    hipLaunchKernelGGL(capsule_kernel, grid, block, 0, stream, x, w, out);
}